// Round 7
// baseline (1838.835 us; speedup 1.0000x reference)
//
#include <hip/hip_runtime.h>

#define S_LEN 2048
#define HID 64

typedef float f32x4 __attribute__((ext_vector_type(4)));
typedef float f32x2 __attribute__((ext_vector_type(2)));

__device__ __forceinline__ float rlane(float v, int l) {
    return __int_as_float(__builtin_amdgcn_readlane(__float_as_int(v), l));
}

__device__ __forceinline__ f32x2 lo2(f32x4 v) { return __builtin_shufflevector(v, v, 0, 1); }
__device__ __forceinline__ f32x2 hi2(f32x4 v) { return __builtin_shufflevector(v, v, 2, 3); }

// v += dpp_moved(v); bound_ctrl=1 -> OOB lanes read 0.
template<int CTRL, int RM>
__device__ __forceinline__ float dpp_add(float v) {
    int t = __builtin_amdgcn_update_dpp(0, __float_as_int(v), CTRL, RM, 0xF, true);
    return v + __int_as_float(t);
}

// sum across 64 lanes -> uniform scalar, VALU-only.
__device__ __forceinline__ float wave_sum(float v) {
    v = dpp_add<0x111, 0xF>(v);  // row_shr:1
    v = dpp_add<0x112, 0xF>(v);  // row_shr:2
    v = dpp_add<0x114, 0xF>(v);  // row_shr:4
    v = dpp_add<0x118, 0xF>(v);  // row_shr:8
    v = dpp_add<0x142, 0xA>(v);  // row_bcast:15
    v = dpp_add<0x143, 0xC>(v);  // row_bcast:31 -> lane63 holds total
    return rlane(v, 63);
}

// rotate a 32-bit value right by 1 lane within each 16-lane row:
// dst[n] = src[(n-1)&15]  (row_ror:1 = 0x121)
__device__ __forceinline__ float ror1(float v) {
    return __int_as_float(__builtin_amdgcn_update_dpp(0, __float_as_int(v), 0x121, 0xF, 0xF, false));
}
__device__ __forceinline__ f32x4 ror1q(f32x4 v) {
    f32x4 r; r.x = ror1(v.x); r.y = ror1(v.y); r.z = ror1(v.z); r.w = ror1(v.w);
    return r;
}

__global__ __launch_bounds__(256, 1) void rnn_garch_kernel(
    const float* __restrict__ res,   // (B, S)
    const float* __restrict__ Wih,   // (64, 2)
    const float* __restrict__ bih,   // (64,)
    const float* __restrict__ Whh,   // (64, 64)
    const float* __restrict__ bhh,   // (64,)
    const float* __restrict__ fcw,   // (64,)
    const float* __restrict__ fcb,   // (1,)
    float* __restrict__ out)         // (B, S)
{
    const int lane = threadIdx.x & 63;
    const int wave = threadIdx.x >> 6;
    const int b = blockIdx.x * 4 + wave;
    const int r = lane & 15;

    const float* __restrict__ row = res + (size_t)b * S_LEN;
    float* __restrict__ orow = out + (size_t)b * S_LEN;

    // per-wave h broadcast buffer (wave-private region; no cross-wave sync)
    __shared__ __align__(16) float hb[4][HID];

    // lane j holds row j of W_hh, quads PRE-ROTATED to match the DPP
    // circulation: at rotation step s lane holds h-quad (r-s)&15, so
    // wq[s] = row_quad[(r-s)&15].
    const f32x4* wr = (const f32x4*)(Whh + lane * HID);
    f32x4 wq0  = wr[(r -  0) & 15], wq1  = wr[(r -  1) & 15];
    f32x4 wq2  = wr[(r -  2) & 15], wq3  = wr[(r -  3) & 15];
    f32x4 wq4  = wr[(r -  4) & 15], wq5  = wr[(r -  5) & 15];
    f32x4 wq6  = wr[(r -  6) & 15], wq7  = wr[(r -  7) & 15];
    f32x4 wq8  = wr[(r -  8) & 15], wq9  = wr[(r -  9) & 15];
    f32x4 wq10 = wr[(r - 10) & 15], wq11 = wr[(r - 11) & 15];
    f32x4 wq12 = wr[(r - 12) & 15], wq13 = wr[(r - 13) & 15];
    f32x4 wq14 = wr[(r - 14) & 15], wq15 = wr[(r - 15) & 15];
    // Pin: opaque to the compiler -> cannot be re-loaded from memory in-loop.
    asm("" : "+v"(wq0), "+v"(wq1), "+v"(wq2), "+v"(wq3),
             "+v"(wq4), "+v"(wq5), "+v"(wq6), "+v"(wq7),
             "+v"(wq8), "+v"(wq9), "+v"(wq10), "+v"(wq11),
             "+v"(wq12), "+v"(wq13), "+v"(wq14), "+v"(wq15));

    const float wih0 = Wih[lane * 2 + 0];
    const float wih1 = Wih[lane * 2 + 1];
    const float basb = bih[lane] + bhh[lane];
    const float fw   = fcw[lane];
    const float fb   = fcb[0];

    // ---- sigma0 = var(row, ddof=1) ----
    float s1 = 0.f, s2 = 0.f;
#pragma unroll 8
    for (int i = 0; i < S_LEN / 64; ++i) {
        const float x = row[i * 64 + lane];
        s1 += x;
        s2 = fmaf(x, x, s2);
    }
    s1 = wave_sum(s1);
    s2 = wave_sum(s2);
    const float mean = s1 * (1.0f / S_LEN);
    float sigma = (s2 - s1 * mean) * (1.0f / (S_LEN - 1));

    float vout = (lane == 0) ? sigma : 0.f;   // out[b][0] = sigma0

    // eps^2 double-buffer: squared once per 64-step window
    float en = row[64 + lane];
    float eq = row[lane] * row[lane];

    float* hbw = &hb[wave][0];
    const f32x4* hbq = (const f32x4*)hbw;
    hbw[lane] = 0.f;                 // h_0 = 0

#define MVS(S, W) { \
    A0 = __builtin_elementwise_fma(lo2(W), lo2(hq), A0); \
    A1 = __builtin_elementwise_fma(hi2(W), hi2(hq), A1); \
    hq = ror1q(hq); }
#define MVL(W) { \
    A0 = __builtin_elementwise_fma(lo2(W), lo2(hq), A0); \
    A1 = __builtin_elementwise_fma(hi2(W), hi2(hq), A1); }

#pragma unroll 2
    for (int t = 1; t < S_LEN; ++t) {
        const int idx = (t - 1) & 63;
        if (idx == 0 && t > 1) {            // wave-uniform window advance
            eq = en * en;
            const int nb = ((t - 1) >> 6) + 1;
            if (nb < S_LEN / 64) en = row[nb * 64 + lane];
        }
        const float e2 = rlane(eq, idx);

        // lane i reads h-quad (i&15); lanes 16/32/48 aliases are broadcast
        f32x4 hq = hbq[r];                  // single ds_read_b128

        f32x2 A0; A0.x = fmaf(e2, wih0, basb); A0.y = 0.f;
        f32x2 A1 = {0.f, 0.f};
        MVS(0,  wq0)  MVS(1,  wq1)  MVS(2,  wq2)  MVS(3,  wq3)
        MVS(4,  wq4)  MVS(5,  wq5)  MVS(6,  wq6)  MVS(7,  wq7)
        MVS(8,  wq8)  MVS(9,  wq9)  MVS(10, wq10) MVS(11, wq11)
        MVS(12, wq12) MVS(13, wq13) MVS(14, wq14) MVL(wq15)
        const f32x2 As = A0 + A1;
        // sigma (prev step) enters last -> its chain hides under the fma issue
        const float h = fmaf(sigma, wih1, As.x + As.y);

        // write h for next step NOW; LDS latency overlaps wave_sum+softplus
        hbw[lane] = h;                      // single ds_write_b32

        // x = fc . h + fc_b  (uniform scalar in all lanes)
        const float x = wave_sum(fw * h) + fb;

        // softplus(x) = max(x,0) + log(1 + exp(-|x|)) via v_exp/v_log
        const float e = __expf(-fabsf(x));
        sigma = fmaxf(x, 0.f) + __logf(1.0f + e) + 1e-6f;

        // stage sigma_t into lane (t&63); coalesced store each 64 steps
        if ((t & 63) == lane) vout = sigma;
        if ((t & 63) == 63) orow[(t - 63) + lane] = vout;
    }
#undef MVS
#undef MVL
}

extern "C" void kernel_launch(void* const* d_in, const int* in_sizes, int n_in,
                              void* d_out, int out_size, void* d_ws, size_t ws_size,
                              hipStream_t stream) {
    const float* res = (const float*)d_in[0];
    const float* Wih = (const float*)d_in[1];
    const float* bih = (const float*)d_in[2];
    const float* Whh = (const float*)d_in[3];
    const float* bhh = (const float*)d_in[4];
    const float* fcw = (const float*)d_in[5];
    const float* fcb = (const float*)d_in[6];
    float* out = (float*)d_out;

    const int B = 2048;
    dim3 grid(B / 4), block(256);
    hipLaunchKernelGGL(rnn_garch_kernel, grid, block, 0, stream,
                       res, Wih, bih, Whh, bhh, fcw, fcb, out);
}

// Round 8
// 921.396 us; speedup vs baseline: 1.9957x; 1.9957x over previous
//
#include <hip/hip_runtime.h>

#define S_LEN 2048
#define HID 64

typedef float f32x4 __attribute__((ext_vector_type(4)));
typedef float f32x2 __attribute__((ext_vector_type(2)));

__device__ __forceinline__ float rlane(float v, int l) {
    return __int_as_float(__builtin_amdgcn_readlane(__float_as_int(v), l));
}
__device__ __forceinline__ f32x2 lo2(f32x4 v) { return __builtin_shufflevector(v, v, 0, 1); }
__device__ __forceinline__ f32x2 hi2(f32x4 v) { return __builtin_shufflevector(v, v, 2, 3); }

// v += dpp_moved(v); bound_ctrl=1 -> OOB lanes read 0.
template<int CTRL, int RM>
__device__ __forceinline__ float dpp_add(float v) {
    int t = __builtin_amdgcn_update_dpp(0, __float_as_int(v), CTRL, RM, 0xF, true);
    return v + __int_as_float(t);
}

// sum across 64 lanes -> uniform scalar, VALU-only.
__device__ __forceinline__ float wave_sum(float v) {
    v = dpp_add<0x111, 0xF>(v);  // row_shr:1
    v = dpp_add<0x112, 0xF>(v);  // row_shr:2
    v = dpp_add<0x114, 0xF>(v);  // row_shr:4
    v = dpp_add<0x118, 0xF>(v);  // row_shr:8
    v = dpp_add<0x142, 0xA>(v);  // row_bcast:15
    v = dpp_add<0x143, 0xC>(v);  // row_bcast:31 -> lane63 holds total
    return rlane(v, 63);
}

// v += quad_perm(v): xor1 = [1,0,3,2] = 0xB1, xor2 = [2,3,0,1] = 0x4E
template<int CTRL>
__device__ __forceinline__ float qp_add(float v) {
    int t = __builtin_amdgcn_update_dpp(0, __float_as_int(v), CTRL, 0xF, 0xF, true);
    return v + __int_as_float(t);
}

__global__ __launch_bounds__(256, 2) void rnn_garch_kernel(
    const float* __restrict__ res,   // (B, S)
    const float* __restrict__ Wih,   // (64, 2)
    const float* __restrict__ bih,   // (64,)
    const float* __restrict__ Whh,   // (64, 64)
    const float* __restrict__ bhh,   // (64,)
    const float* __restrict__ fcw,   // (64,)
    const float* __restrict__ fcb,   // (1,)
    float* __restrict__ out)         // (B, S)
{
    const int lane = threadIdx.x & 63;
    const int wave = threadIdx.x >> 6;
    const int b = blockIdx.x * 4 + wave;
    const int g = lane >> 2;   // output group: outputs {g, g+16, g+32, g+48}
    const int p = lane & 3;    // K-chunk: k in [16p, 16p+16)

    const float* __restrict__ row = res + (size_t)b * S_LEN;
    float* __restrict__ orow = out + (size_t)b * S_LEN;

    // per-wave h buffer (wave-private; DS ops within a wave are ordered)
    __shared__ __align__(16) float hb[4][HID];

    // wk[i][m] = Whh[16m+g][16p+i] : lane's 64 weights, gathered column-packed
    f32x4 wk[16];
#pragma unroll
    for (int m = 0; m < 4; ++m) {
        const float* wsrc = Whh + ((m << 4) + g) * HID + (p << 4);
#pragma unroll
        for (int i = 0; i < 16; ++i) wk[i][m] = wsrc[i];
    }
    // Pin: opaque to the compiler -> cannot be re-loaded/spilled in-loop.
    asm("" : "+v"(wk[0]), "+v"(wk[1]), "+v"(wk[2]), "+v"(wk[3]),
             "+v"(wk[4]), "+v"(wk[5]), "+v"(wk[6]), "+v"(wk[7]),
             "+v"(wk[8]), "+v"(wk[9]), "+v"(wk[10]), "+v"(wk[11]),
             "+v"(wk[12]), "+v"(wk[13]), "+v"(wk[14]), "+v"(wk[15]));

    // per-lane epilogue params at outputs o_m = 16m+g
    const int o0 = g, o1 = 16 + g, o2 = 32 + g, o3 = 48 + g;
    const f32x2 wih0q01 = {Wih[o0 * 2], Wih[o1 * 2]};
    const f32x2 wih0q23 = {Wih[o2 * 2], Wih[o3 * 2]};
    const f32x2 wih1q01 = {Wih[o0 * 2 + 1], Wih[o1 * 2 + 1]};
    const f32x2 wih1q23 = {Wih[o2 * 2 + 1], Wih[o3 * 2 + 1]};
    const f32x2 basbq01 = {bih[o0] + bhh[o0], bih[o1] + bhh[o1]};
    const f32x2 basbq23 = {bih[o2] + bhh[o2], bih[o3] + bhh[o3]};
    const f32x2 fwq01   = {fcw[o0], fcw[o1]};
    const f32x2 fwq23   = {fcw[o2], fcw[o3]};
    const float fb = fcb[0];

    // ---- sigma0 = var(row, ddof=1) ----
    float s1 = 0.f, s2 = 0.f;
#pragma unroll 8
    for (int i = 0; i < S_LEN / 64; ++i) {
        const float x = row[i * 64 + lane];
        s1 += x;
        s2 = fmaf(x, x, s2);
    }
    s1 = wave_sum(s1);
    s2 = wave_sum(s2);
    const float mean = s1 * (1.0f / S_LEN);
    float sigma = (s2 - s1 * mean) * (1.0f / (S_LEN - 1));

    float vout = (lane == 0) ? sigma : 0.f;   // out[b][0] = sigma0

    // eps^2 double-buffer: squared once per 64-step window
    float en = row[64 + lane];
    float eq = row[lane] * row[lane];

    float* hbw = &hb[wave][0];
    hbw[lane] = 0.f;                           // h_0 = 0
    const f32x4* hbq = (const f32x4*)hbw + (p << 2);  // this lane's chunk: quads 4p..4p+3
    float* hwr = &hb[wave][(p << 4) + g];      // this lane writes h[16p+g]

// one h scalar consumed against one gathered weight quad -> 2 pk_fma
#define MK(AA, BB, HS, W) { const f32x2 hh = {HS, HS}; \
    AA = __builtin_elementwise_fma(lo2(W), hh, AA); \
    BB = __builtin_elementwise_fma(hi2(W), hh, BB); }

#pragma unroll 2
    for (int t = 1; t < S_LEN; ++t) {
        const int idx = (t - 1) & 63;
        if (idx == 0 && t > 1) {            // wave-uniform window advance
            eq = en * en;
            const int nb = ((t - 1) >> 6) + 1;
            if (nb < S_LEN / 64) en = row[nb * 64 + lane];
        }
        const float e2 = rlane(eq, idx);

        // 4 x ds_read_b128: h[16p .. 16p+15]
        const f32x4 hq0 = hbq[0], hq1 = hbq[1], hq2 = hbq[2], hq3 = hbq[3];

        f32x2 A01a = {0.f, 0.f}, A23a = {0.f, 0.f};
        f32x2 A01b = {0.f, 0.f}, A23b = {0.f, 0.f};
        MK(A01a, A23a, hq0.x, wk[0])  MK(A01b, A23b, hq0.y, wk[1])
        MK(A01a, A23a, hq0.z, wk[2])  MK(A01b, A23b, hq0.w, wk[3])
        MK(A01a, A23a, hq1.x, wk[4])  MK(A01b, A23b, hq1.y, wk[5])
        MK(A01a, A23a, hq1.z, wk[6])  MK(A01b, A23b, hq1.w, wk[7])
        MK(A01a, A23a, hq2.x, wk[8])  MK(A01b, A23b, hq2.y, wk[9])
        MK(A01a, A23a, hq2.z, wk[10]) MK(A01b, A23b, hq2.w, wk[11])
        MK(A01a, A23a, hq3.x, wk[12]) MK(A01b, A23b, hq3.y, wk[13])
        MK(A01a, A23a, hq3.z, wk[14]) MK(A01b, A23b, hq3.w, wk[15])
        f32x2 y01 = A01a + A01b;
        f32x2 y23 = A23a + A23b;

        // reduce across K-chunks (lane bits 0-1): quad_perm xor1 + xor2,
        // 4 independent 32-bit chains, 2 levels each (no serial DPP pipeline)
        y01.x = qp_add<0xB1>(y01.x); y01.y = qp_add<0xB1>(y01.y);
        y23.x = qp_add<0xB1>(y23.x); y23.y = qp_add<0xB1>(y23.y);
        y01.x = qp_add<0x4E>(y01.x); y01.y = qp_add<0x4E>(y01.y);
        y23.x = qp_add<0x4E>(y23.x); y23.y = qp_add<0x4E>(y23.y);

        // + b_ih + b_hh + eps^2*Wih[:,0] + sigma*Wih[:,1]
        const f32x2 e2v = {e2, e2};
        const f32x2 sgv = {sigma, sigma};
        f32x2 t01 = __builtin_elementwise_fma(e2v, wih0q01, basbq01);
        t01 = __builtin_elementwise_fma(sgv, wih1q01, t01);
        y01 += t01;
        f32x2 t23 = __builtin_elementwise_fma(e2v, wih0q23, basbq23);
        t23 = __builtin_elementwise_fma(sgv, wih1q23, t23);
        y23 += t23;

        // write h[16p+g] for next step (single ds_write_b32);
        // LDS latency overlaps the wave_sum/softplus tail
        const float hvx = (lane & 2) ? y23.x : y01.x;
        const float hvy = (lane & 2) ? y23.y : y01.y;
        *hwr = (lane & 1) ? hvy : hvx;

        // x = fc . h + fc_b ; each output counted 4x across p-groups -> *0.25
        f32x2 sdot = y01 * fwq01;
        sdot = __builtin_elementwise_fma(y23, fwq23, sdot);
        const float x = fmaf(wave_sum(sdot.x + sdot.y), 0.25f, fb);

        // softplus(x) = max(x,0) + log(1 + exp(-|x|)) via v_exp/v_log
        const float ee = __expf(-fabsf(x));
        sigma = fmaxf(x, 0.f) + __logf(1.0f + ee) + 1e-6f;

        // stage sigma_t into lane (t&63); coalesced store each 64 steps
        if ((t & 63) == lane) vout = sigma;
        if ((t & 63) == 63) orow[(t - 63) + lane] = vout;
    }
#undef MK
}

extern "C" void kernel_launch(void* const* d_in, const int* in_sizes, int n_in,
                              void* d_out, int out_size, void* d_ws, size_t ws_size,
                              hipStream_t stream) {
    const float* res = (const float*)d_in[0];
    const float* Wih = (const float*)d_in[1];
    const float* bih = (const float*)d_in[2];
    const float* Whh = (const float*)d_in[3];
    const float* bhh = (const float*)d_in[4];
    const float* fcw = (const float*)d_in[5];
    const float* fcb = (const float*)d_in[6];
    float* out = (float*)d_out;

    const int B = 2048;
    dim3 grid(B / 4), block(256);
    hipLaunchKernelGGL(rnn_garch_kernel, grid, block, 0, stream,
                       res, Wih, bih, Whh, bhh, fcw, fcb, out);
}